// Round 6
// baseline (91.013 us; speedup 1.0000x reference)
//
#include <hip/hip_runtime.h>

#define B_   256
#define E_   64
#define G_   2000
#define P_   512
#define K2   2048      // G padded to multiple of BK (xb zero-filled)
#define BK   32
#define NS   (K2/BK)   // 64 K-steps
#define PT   64        // p columns per block: 2 wave-slabs of 32

typedef __bf16 bf16x8 __attribute__((ext_vector_type(8)));
typedef float floatx16 __attribute__((ext_vector_type(16)));
typedef unsigned int u32;

__global__ __launch_bounds__(256)
void cvt_x_kernel(const float* __restrict__ x, __bf16* __restrict__ xb) {
    int col = blockIdx.x * 256 + threadIdx.x;   // 0..2047
    int row = blockIdx.y;
    float v = (col < G_) ? x[(size_t)row * G_ + col] : 0.f;
    xb[(size_t)row * K2 + col] = (__bf16)v;
}

// async global->LDS, 16B per lane, linear LDS dest (uniform base + lane*16)
__device__ __forceinline__ void gll16(const void* g, void* l) {
    __builtin_amdgcn_global_load_lds(
        (const __attribute__((address_space(1))) u32*)(uintptr_t)g,
        (__attribute__((address_space(3))) u32*)(uintptr_t)l,
        16, 0, 0);
}

// Pipeline (T3/T4): raw s_barrier + counted vmcnt, never 0 in main loop.
// Per wave per step: 4 gll16 A (depth-1, L2 source) + 4 gll16 W/M (depth-2,
// HBM source). Top of step s: outstanding = A(s)[4] + WM(s+1)[4] ->
// s_waitcnt vmcnt(4) completes A(s)+WM(s), leaves WM(s+1) in flight across
// the barrier. A: [2][row256][32k] bf16, 64B rows, 16B chunks XOR-swizzled
// by (row>>1)&3 (linear gll dest + pre-swizzled source). W,M: [3][g32][p64]
// f32 linear; B-frags built from LDS (b32 gather bank=p, mul, cvt).
template<bool USE_WS>
__global__ __launch_bounds__(256, 2)
void masked_gemm_kernel(const float* __restrict__ x,
                        const __bf16* __restrict__ xb,
                        const float* __restrict__ weight,
                        const float* __restrict__ bias,
                        const float* __restrict__ mask,
                        float* __restrict__ out)
{
    __shared__ __attribute__((aligned(128))) __bf16 alds[2][B_ * BK];   // 32KB
    __shared__ __attribute__((aligned(128))) float  wlds[3][BK * PT];   // 24KB
    __shared__ __attribute__((aligned(128))) float  mlds[3][BK * PT];   // 24KB

    const int tid  = threadIdx.x;
    const int lane = tid & 63;
    const int wv   = tid >> 6;           // wave: bit0 = row-half, bit1 = p-slab
    const int ln   = lane & 31;
    const int hi   = lane >> 5;          // k-octet half (0..1)

    const int bid = blockIdx.x;          // 512 blocks
    const int pt  = bid & 7;             // p-tile -> XCD (mask slab + xb L2-hot)
    const int e   = bid >> 3;            // expert 0..63
    const int p0  = pt * PT;
    const int pl  = (wv >> 1) * 32 + ln; // p local 0..63
    const int mrow0 = (wv & 1) * 128;

    const float* wbase = weight + (size_t)e * G_ * P_;

    // staging lane coords
    const int arow_l = lane >> 2;        // A: row within 16-row group
    const int aslot  = lane & 3;         // A: 16B chunk slot
    const int wml_g  = lane >> 4;        // WM: g row within 4-row group
    const int wml_p  = (lane & 15) * 4;  // WM: f32 col

    floatx16 acc[4];
    #pragma unroll
    for (int i = 0; i < 4; ++i) acc[i] = (floatx16)0.f;

    auto stageA = [&](int kb, int ab) {
        #pragma unroll
        for (int i = 0; i < 4; ++i) {
            const int r0  = wv * 64 + i * 16;
            const int row = r0 + arow_l;
            const int c   = aslot ^ ((row >> 1) & 3);
            if (USE_WS) {
                gll16(xb + (size_t)row * K2 + kb + c * 8, (void*)&alds[ab][r0 * BK]);
            } else {
                const int k0 = kb + c * 8;
                bf16x8 v;
                #pragma unroll
                for (int j = 0; j < 8; ++j)
                    v[j] = (k0 + j < G_) ? (__bf16)x[(size_t)row * G_ + k0 + j] : (__bf16)0.f;
                *(bf16x8*)&alds[ab][row * BK + aslot * 8] = v;
            }
        }
    };
    auto stageWM = [&](int kb, int wb) {
        #pragma unroll
        for (int i = 0; i < 2; ++i) {
            const int g0 = wv * 8 + i * 4;
            int gg = kb + g0 + wml_g;
            if (gg > G_ - 1) gg = G_ - 1;    // tail clamp: A k-tail is exact 0
            const size_t off = (size_t)gg * P_ + p0 + wml_p;
            if (USE_WS) {
                gll16(wbase + off, (void*)&wlds[wb][g0 * PT]);
                gll16(mask  + off, (void*)&mlds[wb][g0 * PT]);
            } else {
                *(float4*)&wlds[wb][(g0 + wml_g) * PT + wml_p] = *(const float4*)(wbase + off);
                *(float4*)&mlds[wb][(g0 + wml_g) * PT + wml_p] = *(const float4*)(mask + off);
            }
        }
    };

    // ---- prologue: A(0), WM(0), WM(1) -> 12 outstanding ----
    stageA(0, 0);
    stageWM(0, 0);
    stageWM(BK, 1);

    int wmc = 0;                          // s % 3
    for (int s = 0; s < NS; ++s) {
        const int ab = s & 1;

        // counted wait: complete A(s)+WM(s), keep WM(s+1) in flight
        if (s + 1 < NS) { asm volatile("s_waitcnt vmcnt(4)" ::: "memory"); }
        else           { asm volatile("s_waitcnt vmcnt(0)" ::: "memory"); }
        if (!USE_WS)   { asm volatile("s_waitcnt vmcnt(0) lgkmcnt(0)" ::: "memory"); }
        __builtin_amdgcn_s_barrier();
        __builtin_amdgcn_sched_barrier(0);

        // issue next stages (order matters for the vmcnt FIFO count: A first)
        if (s + 1 < NS) stageA((s + 1) * BK, ab ^ 1);
        int wm2 = wmc + 2; if (wm2 >= 3) wm2 -= 3;
        if (s + 2 < NS) stageWM((s + 2) * BK, wm2);

        // build B frags from W/M LDS (b32 gather + mul + cvt)
        bf16x8 bfrag[2];
        #pragma unroll
        for (int kk = 0; kk < 2; ++kk)
            #pragma unroll
            for (int j = 0; j < 8; ++j) {
                const int g = kk * 16 + hi * 8 + j;
                bfrag[kk][j] = (__bf16)(wlds[wmc][g * PT + pl] * mlds[wmc][g * PT + pl]);
            }

        // 8 ds_read_b128 + 8 MFMA(32x32x16)
        #pragma unroll
        for (int kk = 0; kk < 2; ++kk) {
            #pragma unroll
            for (int mi = 0; mi < 4; ++mi) {
                const int row = mrow0 + mi * 32 + ln;
                const int c   = (kk * 2 + hi) ^ ((row >> 1) & 3);
                bf16x8 a = *(const bf16x8*)&alds[ab][row * BK + c * 8];
                acc[mi] = __builtin_amdgcn_mfma_f32_32x32x16_bf16(a, bfrag[kk], acc[mi], 0, 0, 0);
            }
        }

        wmc = (wmc + 1 == 3) ? 0 : wmc + 1;
    }

    // ---- epilogue: D col n=p=lane&31, row m=(r&3)+8*(r>>2)+4*hi ----
    const float bv = bias[e * P_ + p0 + pl];
    #pragma unroll
    for (int mi = 0; mi < 4; ++mi) {
        #pragma unroll
        for (int r = 0; r < 16; ++r) {
            const int b = mrow0 + mi * 32 + (r & 3) + 8 * (r >> 2) + 4 * hi;
            __builtin_nontemporal_store(acc[mi][r] + bv,
                &out[(size_t)b * (E_ * P_) + (size_t)e * P_ + p0 + pl]);
        }
    }
}

extern "C" void kernel_launch(void* const* d_in, const int* in_sizes, int n_in,
                              void* d_out, int out_size, void* d_ws, size_t ws_size,
                              hipStream_t stream) {
    const float* x      = (const float*)d_in[0];
    const float* weight = (const float*)d_in[1];
    const float* bias   = (const float*)d_in[2];
    const float* mask   = (const float*)d_in[3];
    float* out = (float*)d_out;

    const size_t xb_bytes = (size_t)B_ * K2 * sizeof(__bf16);
    if (ws_size >= xb_bytes) {
        __bf16* xb = (__bf16*)d_ws;
        dim3 g1(K2 / 256, B_);
        cvt_x_kernel<<<g1, dim3(256), 0, stream>>>(x, xb);
        masked_gemm_kernel<true><<<dim3(512), dim3(256), 0, stream>>>(x, xb, weight, bias, mask, out);
    } else {
        masked_gemm_kernel<false><<<dim3(512), dim3(256), 0, stream>>>(x, nullptr, weight, bias, mask, out);
    }
}